// Round 10
// baseline (8416.628 us; speedup 1.0000x reference)
//
#include <hip/hip_runtime.h>
#include <hip/hip_bf16.h>
#include <math.h>

#define B_   128
#define S_   1024
#define I_   512
#define H_   1024
#define KC   1536
#define NWG  256
#define NTHR 512

typedef __bf16 v8bf __attribute__((ext_vector_type(8)));
typedef float  v4f  __attribute__((ext_vector_type(4)));
typedef unsigned long long ull;

// XOR swizzle on bf16 element index within a row: spreads 16B granules.
__device__ __forceinline__ int swz(int row, int e) { return e ^ ((row & 7) << 3); }

__device__ __forceinline__ v8bf cvt8(const float4 a, const float4 b) {
    v8bf r;
    r[0] = (__bf16)a.x; r[1] = (__bf16)a.y; r[2] = (__bf16)a.z; r[3] = (__bf16)a.w;
    r[4] = (__bf16)b.x; r[5] = (__bf16)b.y; r[6] = (__bf16)b.z; r[7] = (__bf16)b.w;
    return r;
}

__device__ __forceinline__ float sigm(float x) { return 1.f / (1.f + __expf(-x)); }
__device__ __forceinline__ float tanh_fast(float x) {
    const float xc = fminf(fmaxf(x, -15.f), 15.f);
    const float e  = __expf(2.f * xc);
    return (e - 1.f) / (e + 1.f);
}

// Pack W_ih||W_hh (fp32) -> Wc bf16 [4096][1536] row-major.
__global__ void lstm_pack(const float* __restrict__ Wih, const float* __restrict__ Whh,
                          __bf16* __restrict__ Wc)
{
    const size_t e = ((size_t)blockIdx.x * 256 + threadIdx.x) * 8;
    const int col = (int)(e / KC);
    const int k   = (int)(e % KC);
    const float4* src = (k < I_) ? (const float4*)&Wih[(size_t)col * I_ + k]
                                 : (const float4*)&Whh[(size_t)col * H_ + (k - I_)];
    const float4 a = src[0], b = src[1];
    *(v8bf*)&Wc[e] = cvt8(a, b);
}

// Persistent LSTM. 256 WGs: bg=wg&7 (8 batch groups of 16 rows, each on ONE
// XCD), cg=wg>>3 (32 col groups of 32 h-cols). 8 waves = (ks in 0..3 K-slice,
// nh in 0..1 col-half). Each wave: 16 gate-cols x 4 gates. W_hh (recurrent,
// critical path) resident in registers: wh[4][8] v8bf = 128 regs/wave. W_ih
// streamed from L2 each step but its MFMA runs in the post-publish shadow.
// A-fragments reused across 4 gates -> 12 LDS A-reads/wave/step.
__global__ __launch_bounds__(NTHR, 1) void lstm_persist(
    const float* __restrict__ seq, const int* __restrict__ len,
    const __bf16* __restrict__ Wc,
    const float* __restrict__ bih, const float* __restrict__ bhh,
    float* __restrict__ out, __bf16* __restrict__ hA, __bf16* __restrict__ hB,
    unsigned* __restrict__ flg)
{
    __shared__ __bf16 xpan[2][16 * 512];    // double-buffered x panels (swizzled)
    __shared__ __bf16 hpan[16 * 1024];      // h_{t-1} (swizzled)
    __shared__ float  glds[4][4][16][33];   // [gate][ks][row][col+pad]

    const int wg   = blockIdx.x;
    const int bg   = wg & 7;     // batch group: rows bg*16+[0,16) (XCD-local)
    const int cg   = wg >> 3;    // col group: h-cols cg*32+[0,32)
    const int tid  = threadIdx.x;
    const int lane = tid & 63;
    const int wv   = tid >> 6;
    const int l15  = lane & 15;
    const int q    = lane >> 4;
    const int ks   = wv & 3;     // K-slice: k-tiles kt with kt%4 == ks
    const int nh   = wv >> 2;    // col half: cols nh*16+[0,16)

    // per-gate weight pointers at this lane's (col, k-phase)
    const __bf16* wp[4];
    float bb[4];
    #pragma unroll
    for (int g = 0; g < 4; ++g) {
        const int colg = g * H_ + cg * 32 + nh * 16 + l15;
        wp[g] = Wc + (size_t)colg * KC + ks * 32 + q * 8;
        bb[g] = (ks == 0) ? (bih[colg] + bhh[colg]) : 0.f;
    }

    // ---- one-time: resident recurrent weights wh[g][m] (k-tile 16+ks+4m) ----
    v8bf wh[4][8];
    #pragma unroll
    for (int g = 0; g < 4; ++g) {
        #pragma unroll
        for (int m = 0; m < 8; ++m)
            wh[g][m] = *(const v8bf*)(wp[g] + 512 + m * 128);
    }
    #pragma unroll
    for (int g = 0; g < 4; ++g) {
        #pragma unroll
        for (int m = 0; m < 8; ++m)
            asm volatile("" : "+v"(wh[g][m]));
    }

    // ---- per-thread roles ----
    const int xr   = tid & 15;   // staging row [0,16)
    const int xseg = tid >> 4;   // staging 32-elem segment [0,32)
    const int urow = tid >> 5;   // update cell row [0,16)
    const int ucol = tid & 31;   // update cell col [0,32)
    const int gb   = bg * 16 + urow;
    const int gc   = cg * 32 + ucol;
    const int mylen = len[gb];
    float creg = 0.f;

    const float* srow = seq + (size_t)(bg * 16 + xr) * (S_ * I_) + xseg * 16;

    // ---- prologue: stage x_0, acc = bias + x-part(0) ----
    {
        const float4* xs = (const float4*)srow;
        const float4 f0 = xs[0], f1 = xs[1], f2 = xs[2], f3 = xs[3];
        *(v8bf*)&xpan[0][xr * 512 + swz(xr, xseg * 16)]     = cvt8(f0, f1);
        *(v8bf*)&xpan[0][xr * 512 + swz(xr, xseg * 16 + 8)] = cvt8(f2, f3);
    }
    __syncthreads();

    v4f acc[4];
    #pragma unroll
    for (int g = 0; g < 4; ++g) acc[g] = (v4f){bb[g], bb[g], bb[g], bb[g]};
    #pragma unroll
    for (int m = 0; m < 4; ++m) {
        const int e = (ks + 4 * m) * 32 + q * 8;
        const v8bf a = *(const v8bf*)&xpan[0][l15 * 512 + swz(l15, e)];
        #pragma unroll
        for (int g = 0; g < 4; ++g) {
            const v8bf wx = *(const v8bf*)(wp[g] + m * 128);
            acc[g] = __builtin_amdgcn_mfma_f32_16x16x32_bf16(a, wx, acc[g], 0, 0, 0);
        }
    }

    for (int t = 0; t < S_; ++t) {
        const int buf = t & 1;
        const __bf16* hrd = buf ? hA : hB;   // h_{t-1}
        __bf16*       hwr = buf ? hB : hA;   // h_t
        const bool pf = (t + 1 < S_);

        // ---- stage x_{t+1} into the other panel ----
        if (pf) {
            const float4* xs = (const float4*)(srow + (size_t)(t + 1) * I_);
            const float4 f0 = xs[0], f1 = xs[1], f2 = xs[2], f3 = xs[3];
            *(v8bf*)&xpan[buf ^ 1][xr * 512 + swz(xr, xseg * 16)]     = cvt8(f0, f1);
            *(v8bf*)&xpan[buf ^ 1][xr * 512 + swz(xr, xseg * 16 + 8)] = cvt8(f2, f3);
        }

        // ---- poll: all 32 WGs of this bg published h_{t-1} ----
        if (t > 0 && wv == 0) {
            const unsigned* f = flg + bg * 32;
            unsigned v;
            do {
                v = __hip_atomic_load(&f[lane & 31], __ATOMIC_RELAXED,
                                      __HIP_MEMORY_SCOPE_AGENT);
            } while (!__all((int)(v >= (unsigned)t)));
        }
        __syncthreads();  // b1

        // ---- h_{t-1} -> hpan (coherent 8B atomic loads, swizzled land) ----
        {
            const ull* hs = (const ull*)(hrd + (size_t)(bg * 16) * H_);
            ull hv[8];
            #pragma unroll
            for (int j = 0; j < 8; ++j)
                hv[j] = __hip_atomic_load(&hs[xr * 256 + xseg * 8 + j],
                                          __ATOMIC_RELAXED, __HIP_MEMORY_SCOPE_AGENT);
            #pragma unroll
            for (int j = 0; j < 8; ++j)
                *(ull*)&hpan[xr * 1024 + swz(xr, xseg * 32 + j * 4)] = hv[j];
        }
        __syncthreads();  // b2

        // ---- h-MFMA: 8 k-tiles, each A-frag feeds 4 gates ----
        #pragma unroll
        for (int m = 0; m < 8; ++m) {
            const int e = (ks + 4 * m) * 32 + q * 8;
            const v8bf a = *(const v8bf*)&hpan[l15 * 1024 + swz(l15, e)];
            #pragma unroll
            for (int g = 0; g < 4; ++g)
                acc[g] = __builtin_amdgcn_mfma_f32_16x16x32_bf16(a, wh[g][m],
                                                                 acc[g], 0, 0, 0);
        }

        // ---- exchange partials ----
        #pragma unroll
        for (int g = 0; g < 4; ++g) {
            #pragma unroll
            for (int r = 0; r < 4; ++r)
                glds[g][ks][q * 4 + r][nh * 16 + l15] = acc[g][r];
        }
        __syncthreads();  // b3

        // ---- cell update (4-way ks reduction) ----
        const float ig = glds[0][0][urow][ucol] + glds[0][1][urow][ucol]
                       + glds[0][2][urow][ucol] + glds[0][3][urow][ucol];
        const float fg = glds[1][0][urow][ucol] + glds[1][1][urow][ucol]
                       + glds[1][2][urow][ucol] + glds[1][3][urow][ucol];
        const float gg = glds[2][0][urow][ucol] + glds[2][1][urow][ucol]
                       + glds[2][2][urow][ucol] + glds[2][3][urow][ucol];
        const float og = glds[3][0][urow][ucol] + glds[3][1][urow][ucol]
                       + glds[3][2][urow][ucol] + glds[3][3][urow][ucol];

        const float cn  = sigm(fg) * creg + sigm(ig) * tanh_fast(gg);
        const float hvv = sigm(og) * tanh_fast(cn);
        creg = cn;

        // ---- publish h_t (packed 4B relaxed agent stores) ----
        const unsigned short us = __builtin_bit_cast(unsigned short, (__bf16)hvv);
        const unsigned nb = __shfl_xor((unsigned)us, 1);
        if (!(tid & 1)) {
            const unsigned pair = (unsigned)us | (nb << 16);
            __hip_atomic_store((unsigned*)&hwr[(size_t)gb * H_ + gc], pair,
                               __ATOMIC_RELAXED, __HIP_MEMORY_SCOPE_AGENT);
        }
        if (t == mylen - 1) out[(size_t)gb * H_ + gc] = hvv;

        __syncthreads();  // b4: vmcnt(0) drains h stores

        // ---- single-writer epoch flag ----
        if (tid == 0)
            __hip_atomic_store(&flg[bg * 32 + cg], (unsigned)(t + 1),
                               __ATOMIC_RELAXED, __HIP_MEMORY_SCOPE_AGENT);

        // ---- x-part(t+1) + bias into acc (streamed W_ih, hides under poll) ----
        if (pf) {
            #pragma unroll
            for (int g = 0; g < 4; ++g) acc[g] = (v4f){bb[g], bb[g], bb[g], bb[g]};
            #pragma unroll
            for (int m = 0; m < 4; ++m) {
                const int e = (ks + 4 * m) * 32 + q * 8;
                const v8bf a = *(const v8bf*)&xpan[buf ^ 1][l15 * 512 + swz(l15, e)];
                #pragma unroll
                for (int g = 0; g < 4; ++g) {
                    const v8bf wx = *(const v8bf*)(wp[g] + m * 128);
                    acc[g] = __builtin_amdgcn_mfma_f32_16x16x32_bf16(a, wx,
                                                                     acc[g], 0, 0, 0);
                }
            }
        }
    }
}

extern "C" void kernel_launch(void* const* d_in, const int* in_sizes, int n_in,
                              void* d_out, int out_size, void* d_ws, size_t ws_size,
                              hipStream_t stream) {
    const float* seq = (const float*)d_in[0];
    const int*   len = (const int*)d_in[1];
    const float* Wih = (const float*)d_in[2];
    const float* Whh = (const float*)d_in[3];
    const float* bih = (const float*)d_in[4];
    const float* bhh = (const float*)d_in[5];
    float* out = (float*)d_out;

    char* ws = (char*)d_ws;
    __bf16*   Wc  = (__bf16*)ws;                          // 12,582,912 B
    __bf16*   hA  = (__bf16*)(ws + 12582912);             //    262,144 B
    __bf16*   hB  = (__bf16*)(ws + 12845056);             //    262,144 B
    unsigned* flg = (unsigned*)(ws + 13107200);           //      1,024 B

    hipMemsetAsync(hA, 0, 2 * (size_t)B_ * H_ * sizeof(__bf16), stream);  // hA+hB
    hipMemsetAsync(flg, 0, 8 * 32 * sizeof(unsigned), stream);

    lstm_pack<<<dim3(3072), dim3(256), 0, stream>>>(Wih, Whh, Wc);

    void* args[] = {(void*)&seq, (void*)&len, (void*)&Wc, (void*)&bih,
                    (void*)&bhh, (void*)&out, (void*)&hA, (void*)&hB, (void*)&flg};
    hipError_t e = hipLaunchCooperativeKernel((void*)lstm_persist, dim3(NWG),
                                              dim3(NTHR), args, 0, stream);
    if (e != hipSuccess) {
        lstm_persist<<<dim3(NWG), dim3(NTHR), 0, stream>>>(seq, len, Wc, bih,
                                                           bhh, out, hA, hB, flg);
    }
}